// Round 4
// baseline (504.094 us; speedup 1.0000x reference)
//
#include <hip/hip_runtime.h>
#include <stdint.h>

#define BB 8
#define SS 2048
#define EE 512
#define INV_SCALE 0.04419417382415922f  // 1/sqrt(512)

typedef __attribute__((ext_vector_type(8))) short bf8_t;   // 8 bf16 in 4 VGPRs
typedef __attribute__((ext_vector_type(4))) float f4_t;    // MFMA accumulator

__device__ __forceinline__ unsigned short f2bf(float f) {
    union { float f; uint32_t u; } x; x.f = f;
    uint32_t r = x.u + 0x7fffu + ((x.u >> 16) & 1u);  // RNE
    return (unsigned short)(r >> 16);
}

// ---------------- prep kernels (unchanged) ----------------

__global__ void __launch_bounds__(256) gather_k_kernel(const int* __restrict__ idx,
                                                       const float* __restrict__ emb,
                                                       unsigned short* __restrict__ out) {
    int id = blockIdx.x * 256 + threadIdx.x;   // B*S*(E/8) = 1,048,576
    int chunk = id & 63;                        // E/8 = 64
    int row = id >> 6;                          // 0..B*S-1
    int e0 = chunk * 8;
    int k = idx[row];
    const float* src = emb + (size_t)k * EE + e0;
    float4 a = *(const float4*)(src);
    float4 c = *(const float4*)(src + 4);
    union { unsigned short s[8]; int4 v; } u;
    u.s[0] = f2bf(a.x); u.s[1] = f2bf(a.y); u.s[2] = f2bf(a.z); u.s[3] = f2bf(a.w);
    u.s[4] = f2bf(c.x); u.s[5] = f2bf(c.y); u.s[6] = f2bf(c.z); u.s[7] = f2bf(c.w);
    *(int4*)(out + (size_t)row * EE + e0) = u.v;
}

__global__ void __launch_bounds__(256) cast_h_kernel(const float* __restrict__ in,
                                                     unsigned short* __restrict__ out) {
    int id = blockIdx.x * 256 + threadIdx.x;   // B*S*E/8 = 1,048,576
    const float* src = in + (size_t)id * 8;
    float4 a = *(const float4*)(src);
    float4 c = *(const float4*)(src + 4);
    union { unsigned short s[8]; int4 v; } u;
    u.s[0] = f2bf(a.x); u.s[1] = f2bf(a.y); u.s[2] = f2bf(a.z); u.s[3] = f2bf(a.w);
    u.s[4] = f2bf(c.x); u.s[5] = f2bf(c.y); u.s[6] = f2bf(c.z); u.s[7] = f2bf(c.w);
    *(int4*)(out + (size_t)id * 8) = u.v;
}

__global__ void __launch_bounds__(256) gather_vt_kernel(const int* __restrict__ idx,
                                                        const float* __restrict__ emb,
                                                        unsigned short* __restrict__ vt) {
    int id = blockIdx.x * 256 + threadIdx.x;   // B*E*S = 8,388,608
    int t = id & (SS - 1);
    int rest = id >> 11;                        // /S
    int e = rest & (EE - 1);
    int b = rest >> 9;                          // /E
    int k = idx[b * SS + t];
    vt[id] = f2bf(emb[(size_t)k * EE + e]);
}

__global__ void __launch_bounds__(256) transpose_w_kernel(const float* __restrict__ w,
                                                          unsigned short* __restrict__ wt) {
    int id = blockIdx.x * 256 + threadIdx.x;   // E*E = 262,144
    int e = id & (EE - 1);
    int f = id >> 9;
    wt[id] = f2bf(w[(size_t)e * EE + f] * INV_SCALE);
}

// ---------------- 128x128 MFMA core for qgen (verified rounds 1-3) ----------------

__device__ __forceinline__ void stage_tile(const unsigned short* gbase, int ld, int k0,
                                           unsigned short* lds, int wave, int lane) {
    const int srcchunk = ((lane & 3) ^ ((lane >> 3) & 3)) * 8;
#pragma unroll
    for (int i = 0; i < 2; ++i) {
        int row = i * 64 + wave * 16 + (lane >> 2);
        const unsigned short* g = gbase + (size_t)row * ld + (k0 + srcchunk);
        unsigned short* l = lds + i * 2048 + wave * 512 + lane * 8;  // linear dest
        __builtin_amdgcn_global_load_lds((const __attribute__((address_space(1))) unsigned int*)g,
                                         (__attribute__((address_space(3))) unsigned int*)l,
                                         16, 0, 0);
    }
}

template <int KLEN>
__device__ __forceinline__ void mfma_loop(const unsigned short* Abase, int lda,
                                          const unsigned short* Bbase, int ldb,
                                          unsigned short* As, unsigned short* Bs,
                                          f4_t acc[4][4], int wave, int lane) {
    const int wm = wave >> 1, wn = wave & 1, quad = lane >> 4, l16 = lane & 15;
    const int qs = (quad ^ ((l16 >> 1) & 3)) * 8;
    constexpr int NT = KLEN / 32;

    stage_tile(Abase, lda, 0, As, wave, lane);
    stage_tile(Bbase, ldb, 0, Bs, wave, lane);
    __syncthreads();

    int cur = 0;
#pragma unroll 1
    for (int t = 0; t < NT; ++t) {
        if (t + 1 < NT) {
            stage_tile(Abase, lda, (t + 1) * 32, As + ((cur ^ 1) << 12), wave, lane);
            stage_tile(Bbase, ldb, (t + 1) * 32, Bs + ((cur ^ 1) << 12), wave, lane);
        }
        const unsigned short* a = As + (cur << 12);
        const unsigned short* b = Bs + (cur << 12);
        bf8_t af[4], bfr[4];
#pragma unroll
        for (int mi = 0; mi < 4; ++mi)
            af[mi] = *(const bf8_t*)(a + (wm * 64 + mi * 16 + l16) * 32 + qs);
#pragma unroll
        for (int ni = 0; ni < 4; ++ni)
            bfr[ni] = *(const bf8_t*)(b + (wn * 64 + ni * 16 + l16) * 32 + qs);
#pragma unroll
        for (int mi = 0; mi < 4; ++mi)
#pragma unroll
            for (int ni = 0; ni < 4; ++ni)
                acc[mi][ni] = __builtin_amdgcn_mfma_f32_16x16x32_bf16(af[mi], bfr[ni],
                                                                      acc[mi][ni], 0, 0, 0);
        __syncthreads();
        cur ^= 1;
    }
}

__global__ void __launch_bounds__(256) qgen_kernel(const unsigned short* __restrict__ H,
                                                   const unsigned short* __restrict__ Wt,
                                                   unsigned short* __restrict__ Q) {
    __shared__ unsigned short As[2 * 128 * 32];
    __shared__ unsigned short Bs[2 * 128 * 32];
    const int tid = threadIdx.x, wave = tid >> 6, lane = tid & 63;
    const int rowT = blockIdx.y;
    const int colT = blockIdx.x;
    f4_t acc[4][4];
    const f4_t z = {0.f, 0.f, 0.f, 0.f};
    for (int i = 0; i < 4; ++i) for (int j = 0; j < 4; ++j) acc[i][j] = z;
    mfma_loop<EE>(H + (size_t)rowT * 128 * EE, EE,
                  Wt + (size_t)colT * 128 * EE, EE, As, Bs, acc, wave, lane);
    const int wm = wave >> 1, wn = wave & 1, quad = lane >> 4, l16 = lane & 15;
#pragma unroll
    for (int mi = 0; mi < 4; ++mi)
#pragma unroll
        for (int r = 0; r < 4; ++r) {
            int row = rowT * 128 + wm * 64 + mi * 16 + quad * 4 + r;
#pragma unroll
            for (int ni = 0; ni < 4; ++ni) {
                int col = colT * 128 + wn * 64 + ni * 16 + l16;
                Q[(size_t)row * EE + col] = f2bf(acc[mi][ni][r]);
            }
        }
}

// ---------------- fused QK^T -> exp*mask -> PV kernel ----------------
// One block = 64 q-rows x 512 out-cols, b fixed. 8 waves (512 thr), 2M x 4N.
//   wm = wave>>2 (q-half of 32 rows), wn = wave&3.
// Per t-tile (128 t, 16 tiles):
//   A) QK E-loop: 8 steps BK=64, dbuf LDS, single barrier/step (round-1 shape).
//      Swizzle (rule 21): LDS dest linear; global src chunk c -> c^(row&7);
//      ds_read applies the same XOR (row&7 == l16&7 for frag rows).
//   B) P = exp(S)*clip(mask), bf16 -> Pl (swizzled [64][128]); psum accumulated
//      per-lane in regs (t-slices: l16), cross-ni in-reg.
//   C) PV: Pl as A-frags (swizzle-matched), V-frags as direct 16B global loads
//      from L2-resident Vt (full 64B lines per 4 quads); 16 persistent accs.
// Normalization deferred to the end (reference has no max-subtraction): O/=sum.
// b = blockIdx&7 -> all 32 blocks of a batch on one XCD (L2 locality heuristic).
__global__ void __launch_bounds__(512, 2) attn_fused_kernel(
    const unsigned short* __restrict__ Q,
    const unsigned short* __restrict__ K,
    const unsigned short* __restrict__ Vt,
    const float* __restrict__ mask,
    float* __restrict__ out) {
    __shared__ unsigned short As[2][64 * 64];    // 2 x 8 KB
    __shared__ unsigned short Bs[2][128 * 64];   // 2 x 16 KB
    __shared__ unsigned short Pl[64 * 128];      // 16 KB
    __shared__ float lsum_s[64];

    const int tid = threadIdx.x;
    const int wave = tid >> 6, lane = tid & 63;
    const int wm = wave >> 2, wn = wave & 3;
    const int quad = lane >> 4, l16 = lane & 15;

    const int bid = blockIdx.x;
    const int b = bid & 7, qT = bid >> 3;      // same-b blocks share an XCD

    const unsigned short* Qbase = Q + ((size_t)b * SS + qT * 64) * EE;
    const unsigned short* Kbase = K + (size_t)b * SS * EE;
    const unsigned short* Vbase = Vt + (size_t)b * EE * SS;
    const float* mbase = mask + ((size_t)b * SS + qT * 64) * SS;

    if (tid < 64) lsum_s[tid] = 0.f;   // ordered before use by E-loop barriers

    f4_t pvacc[2][8];
    const f4_t z = {0.f, 0.f, 0.f, 0.f};
#pragma unroll
    for (int i = 0; i < 2; ++i)
#pragma unroll
        for (int j = 0; j < 8; ++j) pvacc[i][j] = z;
    float psum[2][4] = {{0.f, 0.f, 0.f, 0.f}, {0.f, 0.f, 0.f, 0.f}};

    // staging constants: thread -> (row = tid>>3, chunk = tid&7); src chunk XOR'd
    const int srow = tid >> 3;                    // 0..63
    const int scA = ((tid & 7) ^ (srow & 7)) * 8; // swizzled src elem offset

#pragma unroll 1
    for (int tT = 0; tT < 16; ++tT) {
        const unsigned short* Kt = Kbase + (size_t)tT * 128 * EE;

        // ---- phase A: S = Q-tile . K-tile^T (64x128), E-loop ----
        f4_t sacc[2][2];
#pragma unroll
        for (int i = 0; i < 2; ++i)
#pragma unroll
            for (int j = 0; j < 2; ++j) sacc[i][j] = z;

        // prologue: stage step 0 into buf 0
        {
            const unsigned short* gA = Qbase + (size_t)srow * EE + scA;
            __builtin_amdgcn_global_load_lds(
                (const __attribute__((address_space(1))) unsigned int*)gA,
                (__attribute__((address_space(3))) unsigned int*)(&As[0][0] + tid * 8),
                16, 0, 0);
#pragma unroll
            for (int i = 0; i < 2; ++i) {
                const unsigned short* gB = Kt + (size_t)(i * 64 + srow) * EE + scA;
                __builtin_amdgcn_global_load_lds(
                    (const __attribute__((address_space(1))) unsigned int*)gB,
                    (__attribute__((address_space(3))) unsigned int*)(&Bs[0][0] + i * 4096 + tid * 8),
                    16, 0, 0);
            }
        }
        __syncthreads();

        int buf = 0;
#pragma unroll 1
        for (int s = 0; s < 8; ++s) {
            if (s + 1 < 8) {   // stage next step into buf^1 (read 2 barriers ago)
                const int k0 = (s + 1) * 64;
                const unsigned short* gA = Qbase + (size_t)srow * EE + k0 + scA;
                __builtin_amdgcn_global_load_lds(
                    (const __attribute__((address_space(1))) unsigned int*)gA,
                    (__attribute__((address_space(3))) unsigned int*)(&As[buf ^ 1][0] + tid * 8),
                    16, 0, 0);
#pragma unroll
                for (int i = 0; i < 2; ++i) {
                    const unsigned short* gB = Kt + (size_t)(i * 64 + srow) * EE + k0 + scA;
                    __builtin_amdgcn_global_load_lds(
                        (const __attribute__((address_space(1))) unsigned int*)gB,
                        (__attribute__((address_space(3))) unsigned int*)(&Bs[buf ^ 1][0] + i * 4096 + tid * 8),
                        16, 0, 0);
                }
            }
            bf8_t af[2][2], bfv[2][2];
#pragma unroll
            for (int mi = 0; mi < 2; ++mi)
#pragma unroll
                for (int ks = 0; ks < 2; ++ks)
                    af[mi][ks] = *(const bf8_t*)(&As[buf][0] +
                        (wm * 32 + mi * 16 + l16) * 64 + (((ks * 4 + quad) ^ (l16 & 7)) << 3));
#pragma unroll
            for (int ni = 0; ni < 2; ++ni)
#pragma unroll
                for (int ks = 0; ks < 2; ++ks)
                    bfv[ni][ks] = *(const bf8_t*)(&Bs[buf][0] +
                        (wn * 32 + ni * 16 + l16) * 64 + (((ks * 4 + quad) ^ (l16 & 7)) << 3));
#pragma unroll
            for (int ks = 0; ks < 2; ++ks)
#pragma unroll
                for (int mi = 0; mi < 2; ++mi)
#pragma unroll
                    for (int ni = 0; ni < 2; ++ni)
                        sacc[mi][ni] = __builtin_amdgcn_mfma_f32_16x16x32_bf16(
                            af[mi][ks], bfv[ni][ks], sacc[mi][ni], 0, 0, 0);
            __syncthreads();
            buf ^= 1;
        }

        // ---- phase B: P = exp(S)*clip(mask); write Pl (swizzled); psum accum ----
#pragma unroll
        for (int mi = 0; mi < 2; ++mi)
#pragma unroll
            for (int ni = 0; ni < 2; ++ni)
#pragma unroll
                for (int r = 0; r < 4; ++r) {
                    const int row_l = wm * 32 + mi * 16 + quad * 4 + r;
                    const int t_l = wn * 32 + ni * 16 + l16;
                    float m = mbase[(size_t)row_l * SS + tT * 128 + t_l];
                    m = fminf(fmaxf(m, 0.f), 1.f);
                    float e = __expf(sacc[mi][ni][r]) * m;
                    psum[mi][r] += e;
                    const int c = t_l >> 3;
                    Pl[row_l * 128 + ((c ^ (row_l & 7)) << 3) + (t_l & 7)] = f2bf(e);
                }
        __syncthreads();   // Pl visible to all waves

        // ---- phase C: pvacc += P . V ----
#pragma unroll
        for (int ks = 0; ks < 4; ++ks) {
            bf8_t pa[2];
#pragma unroll
            for (int mi = 0; mi < 2; ++mi)
                pa[mi] = *(const bf8_t*)(&Pl[0] +
                    (wm * 32 + mi * 16 + l16) * 128 + (((ks * 4 + quad) ^ (l16 & 7)) << 3));
            bf8_t bv[8];
#pragma unroll
            for (int ni = 0; ni < 8; ++ni)
                bv[ni] = *(const bf8_t*)(Vbase +
                    (size_t)(wn * 128 + ni * 16 + l16) * SS + tT * 128 + ks * 32 + quad * 8);
#pragma unroll
            for (int mi = 0; mi < 2; ++mi)
#pragma unroll
                for (int ni = 0; ni < 8; ++ni)
                    pvacc[mi][ni] = __builtin_amdgcn_mfma_f32_16x16x32_bf16(
                        pa[mi], bv[ni], pvacc[mi][ni], 0, 0, 0);
        }
        __syncthreads();   // P reads done before next tile's phase B overwrites
    }

    // ---- final: row sums across l16 (shuffle) and wn (LDS atomic); write out ----
#pragma unroll
    for (int mi = 0; mi < 2; ++mi)
#pragma unroll
        for (int r = 0; r < 4; ++r) {
            float p = psum[mi][r];
#pragma unroll
            for (int off = 1; off < 16; off <<= 1)
                p += __shfl_xor(p, off, 16);
            if (l16 == 0)
                atomicAdd(&lsum_s[wm * 32 + mi * 16 + quad * 4 + r], p);
        }
    __syncthreads();
#pragma unroll
    for (int mi = 0; mi < 2; ++mi)
#pragma unroll
        for (int r = 0; r < 4; ++r) {
            const int row_l = wm * 32 + mi * 16 + quad * 4 + r;
            const float inv = 1.0f / (lsum_s[row_l] + 1e-10f);
            const size_t orow = ((size_t)b * SS + qT * 64 + row_l) * EE;
#pragma unroll
            for (int ni = 0; ni < 8; ++ni)
                out[orow + wn * 128 + ni * 16 + l16] = pvacc[mi][ni][r] * inv;
        }
}

// ---------------- launcher ----------------

extern "C" void kernel_launch(void* const* d_in, const int* in_sizes, int n_in,
                              void* d_out, int out_size, void* d_ws, size_t ws_size,
                              hipStream_t stream) {
    const int*   key_seq = (const int*)d_in[0];
    const int*   val_seq = (const int*)d_in[1];
    const float* hidden  = (const float*)d_in[2];
    const float* mask    = (const float*)d_in[3];
    // d_in[4] nan_matrix: unused by forward
    const float* key_emb = (const float*)d_in[5];
    const float* val_emb = (const float*)d_in[6];
    const float* weight  = (const float*)d_in[7];
    float* out = (float*)d_out;

    char* ws = (char*)d_ws;
    const size_t SZ_BSE = (size_t)BB * SS * EE * sizeof(unsigned short);  // 16,777,216
    unsigned short* Q  = (unsigned short*)(ws);
    unsigned short* K  = (unsigned short*)(ws + SZ_BSE);
    unsigned short* Vt = (unsigned short*)(ws + 2 * SZ_BSE);
    unsigned short* H  = (unsigned short*)(ws + 3 * SZ_BSE);
    unsigned short* Wt = (unsigned short*)(ws + 4 * SZ_BSE);              // 524,288 B

    gather_k_kernel<<<4096, 256, 0, stream>>>(key_seq, key_emb, K);
    cast_h_kernel<<<4096, 256, 0, stream>>>(hidden, H);
    gather_vt_kernel<<<32768, 256, 0, stream>>>(val_seq, val_emb, Vt);
    transpose_w_kernel<<<1024, 256, 0, stream>>>(weight, Wt);

    qgen_kernel<<<dim3(4, 128), 256, 0, stream>>>(H, Wt, Q);
    attn_fused_kernel<<<256, 512, 0, stream>>>(Q, K, Vt, mask, out);
}

// Round 5
// 428.229 us; speedup vs baseline: 1.1772x; 1.1772x over previous
//
#include <hip/hip_runtime.h>
#include <stdint.h>

#define BB 8
#define SS 2048
#define EE 512
#define INV_SCALE 0.04419417382415922f  // 1/sqrt(512)

typedef __attribute__((ext_vector_type(8))) short bf8_t;   // 8 bf16 in 4 VGPRs
typedef __attribute__((ext_vector_type(4))) float f4_t;    // MFMA accumulator

__device__ __forceinline__ unsigned short f2bf(float f) {
    union { float f; uint32_t u; } x; x.f = f;
    uint32_t r = x.u + 0x7fffu + ((x.u >> 16) & 1u);  // RNE
    return (unsigned short)(r >> 16);
}

// ---------------- prep kernels (unchanged, verified) ----------------

__global__ void __launch_bounds__(256) gather_k_kernel(const int* __restrict__ idx,
                                                       const float* __restrict__ emb,
                                                       unsigned short* __restrict__ out) {
    int id = blockIdx.x * 256 + threadIdx.x;   // B*S*(E/8) = 1,048,576
    int chunk = id & 63;
    int row = id >> 6;
    int e0 = chunk * 8;
    int k = idx[row];
    const float* src = emb + (size_t)k * EE + e0;
    float4 a = *(const float4*)(src);
    float4 c = *(const float4*)(src + 4);
    union { unsigned short s[8]; int4 v; } u;
    u.s[0] = f2bf(a.x); u.s[1] = f2bf(a.y); u.s[2] = f2bf(a.z); u.s[3] = f2bf(a.w);
    u.s[4] = f2bf(c.x); u.s[5] = f2bf(c.y); u.s[6] = f2bf(c.z); u.s[7] = f2bf(c.w);
    *(int4*)(out + (size_t)row * EE + e0) = u.v;
}

__global__ void __launch_bounds__(256) cast_h_kernel(const float* __restrict__ in,
                                                     unsigned short* __restrict__ out) {
    int id = blockIdx.x * 256 + threadIdx.x;   // B*S*E/8 = 1,048,576
    const float* src = in + (size_t)id * 8;
    float4 a = *(const float4*)(src);
    float4 c = *(const float4*)(src + 4);
    union { unsigned short s[8]; int4 v; } u;
    u.s[0] = f2bf(a.x); u.s[1] = f2bf(a.y); u.s[2] = f2bf(a.z); u.s[3] = f2bf(a.w);
    u.s[4] = f2bf(c.x); u.s[5] = f2bf(c.y); u.s[6] = f2bf(c.z); u.s[7] = f2bf(c.w);
    *(int4*)(out + (size_t)id * 8) = u.v;
}

__global__ void __launch_bounds__(256) gather_vt_kernel(const int* __restrict__ idx,
                                                        const float* __restrict__ emb,
                                                        unsigned short* __restrict__ vt) {
    int id = blockIdx.x * 256 + threadIdx.x;   // B*E*S = 8,388,608
    int t = id & (SS - 1);
    int rest = id >> 11;
    int e = rest & (EE - 1);
    int b = rest >> 9;
    int k = idx[b * SS + t];
    vt[id] = f2bf(emb[(size_t)k * EE + e]);
}

__global__ void __launch_bounds__(256) transpose_w_kernel(const float* __restrict__ w,
                                                          unsigned short* __restrict__ wt) {
    int id = blockIdx.x * 256 + threadIdx.x;   // E*E = 262,144
    int e = id & (EE - 1);
    int f = id >> 9;
    wt[id] = f2bf(w[(size_t)e * EE + f] * INV_SCALE);
}

// ---------------- 128x128 m97-style core (round-2 verified, for qgen/pv) ----------------

__device__ __forceinline__ void stage_tile(const unsigned short* gbase, int ld, int k0,
                                           unsigned short* lds, int wave, int lane) {
    const int srcchunk = ((lane & 3) ^ ((lane >> 3) & 3)) * 8;
#pragma unroll
    for (int i = 0; i < 2; ++i) {
        int row = i * 64 + wave * 16 + (lane >> 2);
        const unsigned short* g = gbase + (size_t)row * ld + (k0 + srcchunk);
        unsigned short* l = lds + i * 2048 + wave * 512 + lane * 8;  // linear dest
        __builtin_amdgcn_global_load_lds((const __attribute__((address_space(1))) unsigned int*)g,
                                         (__attribute__((address_space(3))) unsigned int*)l,
                                         16, 0, 0);
    }
}

template <int KLEN>
__device__ __forceinline__ void mfma_loop(const unsigned short* Abase, int lda,
                                          const unsigned short* Bbase, int ldb,
                                          unsigned short* As, unsigned short* Bs,
                                          f4_t acc[4][4], int wave, int lane) {
    const int wm = wave >> 1, wn = wave & 1, quad = lane >> 4, l16 = lane & 15;
    const int qs = (quad ^ ((l16 >> 1) & 3)) * 8;
    constexpr int NT = KLEN / 32;

    stage_tile(Abase, lda, 0, As, wave, lane);
    stage_tile(Bbase, ldb, 0, Bs, wave, lane);
    __syncthreads();

    int cur = 0;
#pragma unroll 1
    for (int t = 0; t < NT; ++t) {
        if (t + 1 < NT) {
            stage_tile(Abase, lda, (t + 1) * 32, As + ((cur ^ 1) << 12), wave, lane);
            stage_tile(Bbase, ldb, (t + 1) * 32, Bs + ((cur ^ 1) << 12), wave, lane);
        }
        const unsigned short* a = As + (cur << 12);
        const unsigned short* b = Bs + (cur << 12);
        bf8_t af[4], bfr[4];
#pragma unroll
        for (int mi = 0; mi < 4; ++mi)
            af[mi] = *(const bf8_t*)(a + (wm * 64 + mi * 16 + l16) * 32 + qs);
#pragma unroll
        for (int ni = 0; ni < 4; ++ni)
            bfr[ni] = *(const bf8_t*)(b + (wn * 64 + ni * 16 + l16) * 32 + qs);
#pragma unroll
        for (int mi = 0; mi < 4; ++mi)
#pragma unroll
            for (int ni = 0; ni < 4; ++ni)
                acc[mi][ni] = __builtin_amdgcn_mfma_f32_16x16x32_bf16(af[mi], bfr[ni],
                                                                      acc[mi][ni], 0, 0, 0);
        __syncthreads();
        cur ^= 1;
    }
}

__global__ void __launch_bounds__(256) qgen_kernel(const unsigned short* __restrict__ H,
                                                   const unsigned short* __restrict__ Wt,
                                                   unsigned short* __restrict__ Q) {
    __shared__ unsigned short As[2 * 128 * 32];
    __shared__ unsigned short Bs[2 * 128 * 32];
    const int tid = threadIdx.x, wave = tid >> 6, lane = tid & 63;
    const int rowT = blockIdx.y;
    const int colT = blockIdx.x;
    f4_t acc[4][4];
    const f4_t z = {0.f, 0.f, 0.f, 0.f};
    for (int i = 0; i < 4; ++i) for (int j = 0; j < 4; ++j) acc[i][j] = z;
    mfma_loop<EE>(H + (size_t)rowT * 128 * EE, EE,
                  Wt + (size_t)colT * 128 * EE, EE, As, Bs, acc, wave, lane);
    const int wm = wave >> 1, wn = wave & 1, quad = lane >> 4, l16 = lane & 15;
#pragma unroll
    for (int mi = 0; mi < 4; ++mi)
#pragma unroll
        for (int r = 0; r < 4; ++r) {
            int row = rowT * 128 + wm * 64 + mi * 16 + quad * 4 + r;
#pragma unroll
            for (int ni = 0; ni < 4; ++ni) {
                int col = colT * 128 + wn * 64 + ni * 16 + l16;
                Q[(size_t)row * EE + col] = f2bf(acc[mi][ni][r]);
            }
        }
}

__global__ void __launch_bounds__(256) pv_kernel(const unsigned short* __restrict__ delta,
                                                 const unsigned short* __restrict__ Vt,
                                                 const float* __restrict__ lsum,
                                                 float* __restrict__ out) {
    __shared__ unsigned short As[2 * 128 * 32];
    __shared__ unsigned short Bs[2 * 128 * 32];
    const int tid = threadIdx.x, wave = tid >> 6, lane = tid & 63;
    const int b = blockIdx.z, qT = blockIdx.y, eT = blockIdx.x;
    f4_t acc[4][4];
    const f4_t z = {0.f, 0.f, 0.f, 0.f};
    for (int i = 0; i < 4; ++i) for (int j = 0; j < 4; ++j) acc[i][j] = z;
    mfma_loop<SS>(delta + ((size_t)b * SS + qT * 128) * SS, SS,
                  Vt + ((size_t)b * EE + eT * 128) * SS, SS, As, Bs, acc, wave, lane);
    const int wm = wave >> 1, wn = wave & 1, quad = lane >> 4, l16 = lane & 15;
#pragma unroll
    for (int mi = 0; mi < 4; ++mi)
#pragma unroll
        for (int r = 0; r < 4; ++r) {
            int row = qT * 128 + wm * 64 + mi * 16 + quad * 4 + r;
            float inv = 1.0f / (lsum[b * SS + row] + 1e-10f);
#pragma unroll
            for (int ni = 0; ni < 4; ++ni) {
                int col = eT * 128 + wn * 64 + ni * 16 + l16;
                out[((size_t)b * SS + row) * EE + col] = acc[mi][ni][r] * inv;
            }
        }
}

// ---------------- qk: 256x256 8-phase template (T3+T4+T5) ----------------
// 512 thr = 8 waves (2M x 4N); per-wave C = 128x64 = acc[8][4]. BK=64 split in
// two 32-wide k-halves; LDS is k-half-major: [dbuf][kh][256 rows][32 elems]
// (each half contiguous 16 KB -> global_load_lds dest stays linear).
// Schedule per iteration (2 K-tiles t0=buf0, t1=buf1; 8 phases):
//   p: (db,ks,nh) reads + 1 half-tile stage     (dead-region verified)
//   p0 (0,0,0) stage t1.B.k1->Bb[1][1] | p1 (0,0,1) stage t2.A.k0->Ab[0][0]
//   p2 (0,1,0) stage t2.B.k0->Bb[0][0] | p3 (0,1,1) stage t2.A.k1->Ab[0][1] +vmcnt(6)
//   p4 (1,0,0) stage t2.B.k1->Bb[0][1] | p5 (1,0,1) stage t3.A.k0->Ab[1][0]
//   p6 (1,1,0) stage t3.B.k0->Bb[1][0] | p7 (1,1,1) stage t3.A.k1->Ab[1][1] +vmcnt(6)
// vmcnt(6) = 2 loads/half x 3 halves in flight (guide formula); guarantees all
// loads issued <= the phase-0 of the current iter are complete. A-frags load at
// nh=0 phases and are register-reused at nh=1. Last iter: stages (tiles 8,9)
// skipped, waits drop to vmcnt(0). Prologue: 7 halves + vmcnt(6) (leaves exactly
// the steady-state 3 halves in flight). Swizzle (rule 21, 0-conflict pattern
// from round 1): src chunk c4 ^= (row>>1)&3, read slot = quad ^ ((l16>>1)&3).

__device__ __forceinline__ void stage_half(const unsigned short* base, int t, int kh,
                                           unsigned short* half_, int tid) {
#pragma unroll
    for (int j = 0; j < 2; ++j) {
        int idx = j * 512 + tid;              // 0..1023 16B-chunks
        int r = idx >> 2, slot = idx & 3;
        int c4 = slot ^ ((r >> 1) & 3);       // source pre-swizzle
        const unsigned short* g = base + (size_t)r * EE + t * 64 + kh * 32 + c4 * 8;
        __builtin_amdgcn_global_load_lds((const __attribute__((address_space(1))) unsigned int*)g,
                                         (__attribute__((address_space(3))) unsigned int*)(half_ + idx * 8),
                                         16, 0, 0);
    }
}

template <int NH, int WAIT>   // WAIT: -1 none, 6 = counted (0 if lastsel)
__device__ __forceinline__ void qk8_phase(const unsigned short* Ah, const unsigned short* Bh,
                                          bf8_t af[8], f4_t acc[8][4],
                                          const unsigned short* sbase, int st, int skh,
                                          unsigned short* sdst, bool sen,
                                          int wm, int wn, int l16, int aslot, int tid,
                                          bool lastsel) {
    if (NH == 0) {
#pragma unroll
        for (int mi = 0; mi < 8; ++mi)
            af[mi] = *(const bf8_t*)(Ah + (wm * 128 + mi * 16 + l16) * 32 + aslot);
    }
    bf8_t b0 = *(const bf8_t*)(Bh + (wn * 64 + NH * 32 + l16) * 32 + aslot);
    bf8_t b1 = *(const bf8_t*)(Bh + (wn * 64 + NH * 32 + 16 + l16) * 32 + aslot);
    if (sen) stage_half(sbase, st, skh, sdst, tid);
    if (WAIT >= 0) {
        if (lastsel) asm volatile("s_waitcnt vmcnt(0)" ::: "memory");
        else         asm volatile("s_waitcnt vmcnt(6)" ::: "memory");
    }
    __builtin_amdgcn_s_barrier();
    asm volatile("s_waitcnt lgkmcnt(0)" ::: "memory");
    __builtin_amdgcn_sched_barrier(0);
    __builtin_amdgcn_s_setprio(1);
#pragma unroll
    for (int mi = 0; mi < 8; ++mi) {
        acc[mi][NH * 2]     = __builtin_amdgcn_mfma_f32_16x16x32_bf16(af[mi], b0, acc[mi][NH * 2], 0, 0, 0);
        acc[mi][NH * 2 + 1] = __builtin_amdgcn_mfma_f32_16x16x32_bf16(af[mi], b1, acc[mi][NH * 2 + 1], 0, 0, 0);
    }
    __builtin_amdgcn_s_setprio(0);
    __builtin_amdgcn_s_barrier();
    __builtin_amdgcn_sched_barrier(0);
}

__global__ void __launch_bounds__(512, 2) qk8_kernel(const unsigned short* __restrict__ Q,
                                                     const unsigned short* __restrict__ K,
                                                     const float* __restrict__ mask,
                                                     unsigned short* __restrict__ delta,
                                                     float* __restrict__ lsum) {
    __shared__ unsigned short Ab[2][2][256 * 32];   // 64 KB
    __shared__ unsigned short Bb[2][2][256 * 32];   // 64 KB
    const int tid = threadIdx.x;
    const int wave = tid >> 6, lane = tid & 63;
    const int wm = wave >> 2, wn = wave & 3;
    const int quad = lane >> 4, l16 = lane & 15;
    const int aslot = (quad ^ ((l16 >> 1) & 3)) * 8;

    const int lin = blockIdx.x;
    const int b = lin & 7;                 // batch -> XCD (round-robin heuristic)
    const int rest = lin >> 3;
    const int tT = rest & 7, qT = rest >> 3;

    const unsigned short* Abase = Q + ((size_t)b * SS + qT * 256) * EE;
    const unsigned short* Bbase = K + ((size_t)b * SS + tT * 256) * EE;

    f4_t acc[8][4];
    const f4_t z = {0.f, 0.f, 0.f, 0.f};
#pragma unroll
    for (int i = 0; i < 8; ++i)
#pragma unroll
        for (int j = 0; j < 4; ++j) acc[i][j] = z;

    // prologue: tile0 fully + tile1 {A.k0, B.k0, A.k1}  (7 halves, 14 loads)
    stage_half(Abase, 0, 0, &Ab[0][0][0], tid);
    stage_half(Bbase, 0, 0, &Bb[0][0][0], tid);
    stage_half(Abase, 0, 1, &Ab[0][1][0], tid);
    stage_half(Bbase, 0, 1, &Bb[0][1][0], tid);
    stage_half(Abase, 1, 0, &Ab[1][0][0], tid);
    stage_half(Bbase, 1, 0, &Bb[1][0][0], tid);
    stage_half(Abase, 1, 1, &Ab[1][1][0], tid);
    asm volatile("s_waitcnt vmcnt(6)" ::: "memory");   // tile0 landed; 3 halves in flight
    __builtin_amdgcn_s_barrier();
    __builtin_amdgcn_sched_barrier(0);

    bf8_t af[8];

#pragma unroll 1
    for (int it = 0; it < 4; ++it) {
        const int t1 = 2 * it + 1, t2 = 2 * it + 2, t3 = 2 * it + 3;
        const bool last = (it == 3);
        qk8_phase<0, -1>(&Ab[0][0][0], &Bb[0][0][0], af, acc, Bbase, t1, 1, &Bb[1][1][0], true,  wm, wn, l16, aslot, tid, last);
        qk8_phase<1, -1>(&Ab[0][0][0], &Bb[0][0][0], af, acc, Abase, t2, 0, &Ab[0][0][0], !last, wm, wn, l16, aslot, tid, last);
        qk8_phase<0, -1>(&Ab[0][1][0], &Bb[0][1][0], af, acc, Bbase, t2, 0, &Bb[0][0][0], !last, wm, wn, l16, aslot, tid, last);
        qk8_phase<1,  6>(&Ab[0][1][0], &Bb[0][1][0], af, acc, Abase, t2, 1, &Ab[0][1][0], !last, wm, wn, l16, aslot, tid, last);
        qk8_phase<0, -1>(&Ab[1][0][0], &Bb[1][0][0], af, acc, Bbase, t2, 1, &Bb[0][1][0], !last, wm, wn, l16, aslot, tid, last);
        qk8_phase<1, -1>(&Ab[1][0][0], &Bb[1][0][0], af, acc, Abase, t3, 0, &Ab[1][0][0], !last, wm, wn, l16, aslot, tid, last);
        qk8_phase<0, -1>(&Ab[1][1][0], &Bb[1][1][0], af, acc, Bbase, t3, 0, &Bb[1][0][0], !last, wm, wn, l16, aslot, tid, last);
        qk8_phase<1,  6>(&Ab[1][1][0], &Bb[1][1][0], af, acc, Abase, t3, 1, &Ab[1][1][0], !last, wm, wn, l16, aslot, tid, last);
    }

    // epilogue: exp * clip(mask), write delta (bf16), row-sum -> global lsum
#pragma unroll
    for (int mi = 0; mi < 8; ++mi) {
#pragma unroll
        for (int r = 0; r < 4; ++r) {
            int row = qT * 256 + wm * 128 + mi * 16 + quad * 4 + r;
            const float* mrow = mask + ((size_t)b * SS + row) * SS;
            unsigned short* drow = delta + ((size_t)b * SS + row) * SS;
            float psum = 0.f;
#pragma unroll
            for (int j = 0; j < 4; ++j) {
                int col = tT * 256 + wn * 64 + j * 16 + l16;
                float m = mrow[col];
                m = fminf(fmaxf(m, 0.f), 1.f);
                float e = __expf(acc[mi][j][r]) * m;
                drow[col] = f2bf(e);
                psum += e;
            }
#pragma unroll
            for (int off = 1; off < 16; off <<= 1)
                psum += __shfl_xor(psum, off, 16);
            if (l16 == 0) atomicAdd(&lsum[b * SS + row], psum);
        }
    }
}

// ---------------- launcher ----------------

extern "C" void kernel_launch(void* const* d_in, const int* in_sizes, int n_in,
                              void* d_out, int out_size, void* d_ws, size_t ws_size,
                              hipStream_t stream) {
    const int*   key_seq = (const int*)d_in[0];
    const int*   val_seq = (const int*)d_in[1];
    const float* hidden  = (const float*)d_in[2];
    const float* mask    = (const float*)d_in[3];
    // d_in[4] nan_matrix: unused by forward
    const float* key_emb = (const float*)d_in[5];
    const float* val_emb = (const float*)d_in[6];
    const float* weight  = (const float*)d_in[7];
    float* out = (float*)d_out;

    char* ws = (char*)d_ws;
    const size_t SZ_BSE = (size_t)BB * SS * EE * sizeof(unsigned short);  // 16,777,216
    unsigned short* Q    = (unsigned short*)(ws);
    unsigned short* K    = (unsigned short*)(ws + SZ_BSE);
    unsigned short* Vt   = (unsigned short*)(ws + 2 * SZ_BSE);
    unsigned short* H    = (unsigned short*)(ws + 3 * SZ_BSE);
    unsigned short* Wt   = (unsigned short*)(ws + 4 * SZ_BSE);            // 524,288 B
    float*          lsum = (float*)(ws + 4 * SZ_BSE + 524288);           // 65,536 B
    unsigned short* delta= (unsigned short*)(ws + 4 * SZ_BSE + 524288 + 65536); // 67,108,864 B

    hipMemsetAsync(lsum, 0, (size_t)BB * SS * sizeof(float), stream);

    gather_k_kernel<<<4096, 256, 0, stream>>>(key_seq, key_emb, K);
    cast_h_kernel<<<4096, 256, 0, stream>>>(hidden, H);
    gather_vt_kernel<<<32768, 256, 0, stream>>>(val_seq, val_emb, Vt);
    transpose_w_kernel<<<1024, 256, 0, stream>>>(weight, Wt);

    qgen_kernel<<<dim3(4, 128), 256, 0, stream>>>(H, Wt, Q);
    qk8_kernel<<<512, 512, 0, stream>>>(Q, K, mask, delta, lsum);
    pv_kernel<<<dim3(4, 16, 8), 256, 0, stream>>>(delta, Vt, lsum, out);
}

// Round 6
// 413.265 us; speedup vs baseline: 1.2198x; 1.0362x over previous
//
#include <hip/hip_runtime.h>
#include <stdint.h>

#define BB 8
#define SS 2048
#define EE 512
#define INV_SCALE 0.04419417382415922f  // 1/sqrt(512)

typedef __attribute__((ext_vector_type(8))) short bf8_t;   // 8 bf16 in 4 VGPRs
typedef __attribute__((ext_vector_type(4))) float f4_t;    // MFMA accumulator

__device__ __forceinline__ unsigned short f2bf(float f) {
    union { float f; uint32_t u; } x; x.f = f;
    uint32_t r = x.u + 0x7fffu + ((x.u >> 16) & 1u);  // RNE
    return (unsigned short)(r >> 16);
}

// ---------------- prep kernels ----------------

__global__ void __launch_bounds__(256) gather_k_kernel(const int* __restrict__ idx,
                                                       const float* __restrict__ emb,
                                                       unsigned short* __restrict__ out) {
    int id = blockIdx.x * 256 + threadIdx.x;   // B*S*(E/8) = 1,048,576
    int chunk = id & 63;
    int row = id >> 6;
    int e0 = chunk * 8;
    int k = idx[row];
    const float* src = emb + (size_t)k * EE + e0;
    float4 a = *(const float4*)(src);
    float4 c = *(const float4*)(src + 4);
    union { unsigned short s[8]; int4 v; } u;
    u.s[0] = f2bf(a.x); u.s[1] = f2bf(a.y); u.s[2] = f2bf(a.z); u.s[3] = f2bf(a.w);
    u.s[4] = f2bf(c.x); u.s[5] = f2bf(c.y); u.s[6] = f2bf(c.z); u.s[7] = f2bf(c.w);
    *(int4*)(out + (size_t)row * EE + e0) = u.v;
}

__global__ void __launch_bounds__(256) cast_h_kernel(const float* __restrict__ in,
                                                     unsigned short* __restrict__ out) {
    int id = blockIdx.x * 256 + threadIdx.x;   // B*S*E/8 = 1,048,576
    const float* src = in + (size_t)id * 8;
    float4 a = *(const float4*)(src);
    float4 c = *(const float4*)(src + 4);
    union { unsigned short s[8]; int4 v; } u;
    u.s[0] = f2bf(a.x); u.s[1] = f2bf(a.y); u.s[2] = f2bf(a.z); u.s[3] = f2bf(a.w);
    u.s[4] = f2bf(c.x); u.s[5] = f2bf(c.y); u.s[6] = f2bf(c.z); u.s[7] = f2bf(c.w);
    *(int4*)(out + (size_t)id * 8) = u.v;
}

// Vt[b][e][t]: 8 t-elements per thread -> one int4 store (was 1 scalar store/thread)
__global__ void __launch_bounds__(256) gather_vt_kernel(const int* __restrict__ idx,
                                                        const float* __restrict__ emb,
                                                        unsigned short* __restrict__ vt) {
    int id = blockIdx.x * 256 + threadIdx.x;   // B*E*(S/8) = 1,048,576
    int t8 = id & 255;                          // S/8 = 256
    int rest = id >> 8;
    int e = rest & (EE - 1);
    int b = rest >> 9;
    int t0 = t8 * 8;
    const int* ib = idx + b * SS + t0;
    union { unsigned short s[8]; int4 v; } u;
#pragma unroll
    for (int j = 0; j < 8; ++j) {
        int k = ib[j];
        u.s[j] = f2bf(emb[(size_t)k * EE + e]);   // 256KB table: L2-resident
    }
    *(int4*)(vt + ((size_t)b * EE + e) * SS + t0) = u.v;
}

__global__ void __launch_bounds__(256) transpose_w_kernel(const float* __restrict__ w,
                                                          unsigned short* __restrict__ wt) {
    int id = blockIdx.x * 256 + threadIdx.x;   // E*E = 262,144
    int e = id & (EE - 1);
    int f = id >> 9;
    wt[id] = f2bf(w[(size_t)e * EE + f] * INV_SCALE);
}

// ---------------- 128x128 m97-style core (verified; used by qgen) ----------------

__device__ __forceinline__ void stage_tile(const unsigned short* gbase, int ld, int k0,
                                           unsigned short* lds, int wave, int lane) {
    const int srcchunk = ((lane & 3) ^ ((lane >> 3) & 3)) * 8;
#pragma unroll
    for (int i = 0; i < 2; ++i) {
        int row = i * 64 + wave * 16 + (lane >> 2);
        const unsigned short* g = gbase + (size_t)row * ld + (k0 + srcchunk);
        unsigned short* l = lds + i * 2048 + wave * 512 + lane * 8;  // linear dest
        __builtin_amdgcn_global_load_lds((const __attribute__((address_space(1))) unsigned int*)g,
                                         (__attribute__((address_space(3))) unsigned int*)l,
                                         16, 0, 0);
    }
}

template <int KLEN>
__device__ __forceinline__ void mfma_loop(const unsigned short* Abase, int lda,
                                          const unsigned short* Bbase, int ldb,
                                          unsigned short* As, unsigned short* Bs,
                                          f4_t acc[4][4], int wave, int lane) {
    const int wm = wave >> 1, wn = wave & 1, quad = lane >> 4, l16 = lane & 15;
    const int qs = (quad ^ ((l16 >> 1) & 3)) * 8;
    constexpr int NT = KLEN / 32;

    stage_tile(Abase, lda, 0, As, wave, lane);
    stage_tile(Bbase, ldb, 0, Bs, wave, lane);
    __syncthreads();

    int cur = 0;
#pragma unroll 1
    for (int t = 0; t < NT; ++t) {
        if (t + 1 < NT) {
            stage_tile(Abase, lda, (t + 1) * 32, As + ((cur ^ 1) << 12), wave, lane);
            stage_tile(Bbase, ldb, (t + 1) * 32, Bs + ((cur ^ 1) << 12), wave, lane);
        }
        const unsigned short* a = As + (cur << 12);
        const unsigned short* b = Bs + (cur << 12);
        bf8_t af[4], bfr[4];
#pragma unroll
        for (int mi = 0; mi < 4; ++mi)
            af[mi] = *(const bf8_t*)(a + (wm * 64 + mi * 16 + l16) * 32 + qs);
#pragma unroll
        for (int ni = 0; ni < 4; ++ni)
            bfr[ni] = *(const bf8_t*)(b + (wn * 64 + ni * 16 + l16) * 32 + qs);
#pragma unroll
        for (int mi = 0; mi < 4; ++mi)
#pragma unroll
            for (int ni = 0; ni < 4; ++ni)
                acc[mi][ni] = __builtin_amdgcn_mfma_f32_16x16x32_bf16(af[mi], bfr[ni],
                                                                      acc[mi][ni], 0, 0, 0);
        __syncthreads();
        cur ^= 1;
    }
}

__global__ void __launch_bounds__(256) qgen_kernel(const unsigned short* __restrict__ H,
                                                   const unsigned short* __restrict__ Wt,
                                                   unsigned short* __restrict__ Q) {
    __shared__ unsigned short As[2 * 128 * 32];
    __shared__ unsigned short Bs[2 * 128 * 32];
    const int tid = threadIdx.x, wave = tid >> 6, lane = tid & 63;
    const int rowT = blockIdx.y;
    const int colT = blockIdx.x;
    f4_t acc[4][4];
    const f4_t z = {0.f, 0.f, 0.f, 0.f};
    for (int i = 0; i < 4; ++i) for (int j = 0; j < 4; ++j) acc[i][j] = z;
    mfma_loop<EE>(H + (size_t)rowT * 128 * EE, EE,
                  Wt + (size_t)colT * 128 * EE, EE, As, Bs, acc, wave, lane);
    const int wm = wave >> 1, wn = wave & 1, quad = lane >> 4, l16 = lane & 15;
#pragma unroll
    for (int mi = 0; mi < 4; ++mi)
#pragma unroll
        for (int r = 0; r < 4; ++r) {
            int row = rowT * 128 + wm * 64 + mi * 16 + quad * 4 + r;
#pragma unroll
            for (int ni = 0; ni < 4; ++ni) {
                int col = colT * 128 + wn * 64 + ni * 16 + l16;
                Q[(size_t)row * EE + col] = f2bf(acc[mi][ni][r]);
            }
        }
}

// ---------------- qk: 256x256 8-phase template (verified round 5) ----------------

__device__ __forceinline__ void stage_half(const unsigned short* base, int t, int kh,
                                           unsigned short* half_, int tid) {
#pragma unroll
    for (int j = 0; j < 2; ++j) {
        int idx = j * 512 + tid;              // 0..1023 16B-chunks
        int r = idx >> 2, slot = idx & 3;
        int c4 = slot ^ ((r >> 1) & 3);       // source pre-swizzle
        const unsigned short* g = base + (size_t)r * EE + t * 64 + kh * 32 + c4 * 8;
        __builtin_amdgcn_global_load_lds((const __attribute__((address_space(1))) unsigned int*)g,
                                         (__attribute__((address_space(3))) unsigned int*)(half_ + idx * 8),
                                         16, 0, 0);
    }
}

template <int NH, int WAIT>   // WAIT: -1 none, 6 = counted (0 if lastsel)
__device__ __forceinline__ void qk8_phase(const unsigned short* Ah, const unsigned short* Bh,
                                          bf8_t af[8], f4_t acc[8][4],
                                          const unsigned short* sbase, int st, int skh,
                                          unsigned short* sdst, bool sen,
                                          int wm, int wn, int l16, int aslot, int tid,
                                          bool lastsel) {
    if (NH == 0) {
#pragma unroll
        for (int mi = 0; mi < 8; ++mi)
            af[mi] = *(const bf8_t*)(Ah + (wm * 128 + mi * 16 + l16) * 32 + aslot);
    }
    bf8_t b0 = *(const bf8_t*)(Bh + (wn * 64 + NH * 32 + l16) * 32 + aslot);
    bf8_t b1 = *(const bf8_t*)(Bh + (wn * 64 + NH * 32 + 16 + l16) * 32 + aslot);
    if (sen) stage_half(sbase, st, skh, sdst, tid);
    if (WAIT >= 0) {
        if (lastsel) asm volatile("s_waitcnt vmcnt(0)" ::: "memory");
        else         asm volatile("s_waitcnt vmcnt(6)" ::: "memory");
    }
    __builtin_amdgcn_s_barrier();
    asm volatile("s_waitcnt lgkmcnt(0)" ::: "memory");
    __builtin_amdgcn_sched_barrier(0);
    __builtin_amdgcn_s_setprio(1);
#pragma unroll
    for (int mi = 0; mi < 8; ++mi) {
        acc[mi][NH * 2]     = __builtin_amdgcn_mfma_f32_16x16x32_bf16(af[mi], b0, acc[mi][NH * 2], 0, 0, 0);
        acc[mi][NH * 2 + 1] = __builtin_amdgcn_mfma_f32_16x16x32_bf16(af[mi], b1, acc[mi][NH * 2 + 1], 0, 0, 0);
    }
    __builtin_amdgcn_s_setprio(0);
    __builtin_amdgcn_s_barrier();
    __builtin_amdgcn_sched_barrier(0);
}

__global__ void __launch_bounds__(512, 2) qk8_kernel(const unsigned short* __restrict__ Q,
                                                     const unsigned short* __restrict__ K,
                                                     const float* __restrict__ mask,
                                                     unsigned short* __restrict__ delta,
                                                     float* __restrict__ lsum) {
    __shared__ unsigned short Ab[2][2][256 * 32];   // 64 KB
    __shared__ unsigned short Bb[2][2][256 * 32];   // 64 KB
    const int tid = threadIdx.x;
    const int wave = tid >> 6, lane = tid & 63;
    const int wm = wave >> 2, wn = wave & 3;
    const int quad = lane >> 4, l16 = lane & 15;
    const int aslot = (quad ^ ((l16 >> 1) & 3)) * 8;

    const int lin = blockIdx.x;
    const int b = lin & 7;
    const int rest = lin >> 3;
    const int tT = rest & 7, qT = rest >> 3;

    const unsigned short* Abase = Q + ((size_t)b * SS + qT * 256) * EE;
    const unsigned short* Bbase = K + ((size_t)b * SS + tT * 256) * EE;

    f4_t acc[8][4];
    const f4_t z = {0.f, 0.f, 0.f, 0.f};
#pragma unroll
    for (int i = 0; i < 8; ++i)
#pragma unroll
        for (int j = 0; j < 4; ++j) acc[i][j] = z;

    stage_half(Abase, 0, 0, &Ab[0][0][0], tid);
    stage_half(Bbase, 0, 0, &Bb[0][0][0], tid);
    stage_half(Abase, 0, 1, &Ab[0][1][0], tid);
    stage_half(Bbase, 0, 1, &Bb[0][1][0], tid);
    stage_half(Abase, 1, 0, &Ab[1][0][0], tid);
    stage_half(Bbase, 1, 0, &Bb[1][0][0], tid);
    stage_half(Abase, 1, 1, &Ab[1][1][0], tid);
    asm volatile("s_waitcnt vmcnt(6)" ::: "memory");
    __builtin_amdgcn_s_barrier();
    __builtin_amdgcn_sched_barrier(0);

    bf8_t af[8];

#pragma unroll 1
    for (int it = 0; it < 4; ++it) {
        const int t1 = 2 * it + 1, t2 = 2 * it + 2, t3 = 2 * it + 3;
        const bool last = (it == 3);
        qk8_phase<0, -1>(&Ab[0][0][0], &Bb[0][0][0], af, acc, Bbase, t1, 1, &Bb[1][1][0], true,  wm, wn, l16, aslot, tid, last);
        qk8_phase<1, -1>(&Ab[0][0][0], &Bb[0][0][0], af, acc, Abase, t2, 0, &Ab[0][0][0], !last, wm, wn, l16, aslot, tid, last);
        qk8_phase<0, -1>(&Ab[0][1][0], &Bb[0][1][0], af, acc, Bbase, t2, 0, &Bb[0][0][0], !last, wm, wn, l16, aslot, tid, last);
        qk8_phase<1,  6>(&Ab[0][1][0], &Bb[0][1][0], af, acc, Abase, t2, 1, &Ab[0][1][0], !last, wm, wn, l16, aslot, tid, last);
        qk8_phase<0, -1>(&Ab[1][0][0], &Bb[1][0][0], af, acc, Bbase, t2, 1, &Bb[0][1][0], !last, wm, wn, l16, aslot, tid, last);
        qk8_phase<1, -1>(&Ab[1][0][0], &Bb[1][0][0], af, acc, Abase, t3, 0, &Ab[1][0][0], !last, wm, wn, l16, aslot, tid, last);
        qk8_phase<0, -1>(&Ab[1][1][0], &Bb[1][1][0], af, acc, Bbase, t3, 0, &Bb[1][0][0], !last, wm, wn, l16, aslot, tid, last);
        qk8_phase<1,  6>(&Ab[1][1][0], &Bb[1][1][0], af, acc, Abase, t3, 1, &Ab[1][1][0], !last, wm, wn, l16, aslot, tid, last);
    }

#pragma unroll
    for (int mi = 0; mi < 8; ++mi) {
#pragma unroll
        for (int r = 0; r < 4; ++r) {
            int row = qT * 256 + wm * 128 + mi * 16 + quad * 4 + r;
            const float* mrow = mask + ((size_t)b * SS + row) * SS;
            unsigned short* drow = delta + ((size_t)b * SS + row) * SS;
            float psum = 0.f;
#pragma unroll
            for (int j = 0; j < 4; ++j) {
                int col = tT * 256 + wn * 64 + j * 16 + l16;
                float m = mrow[col];
                m = fminf(fmaxf(m, 0.f), 1.f);
                float e = __expf(acc[mi][j][r]) * m;
                drow[col] = f2bf(e);
                psum += e;
            }
#pragma unroll
            for (int off = 1; off < 16; off <<= 1)
                psum += __shfl_xor(psum, off, 16);
            if (l16 == 0) atomicAdd(&lsum[b * SS + row], psum);
        }
    }
}

// ---------------- pv: 256x128 4-phase counted-vmcnt template ----------------
// 512 thr = 8 waves (2M x 4N); wave tile 128x32 -> acc[8][2]. K=2048, BK=64 in
// two kh halves; LDS quad regions Ab[db][kh] (16 KB each) + Bb[db][kh] (8 KB) =
// 96 KB. Phase(db,kh) = {8 A + 2 B ds_reads || stage A-half(2)+B-half(1) ->
// vmcnt(6) -> barrier -> lgkmcnt(0) -> setprio(1) 16 MFMA setprio(0) -> barrier}.
// Dead-region schedule (stage targets region read one barrier earlier):
//   p0 reads [0][0], stages t1.kh1->[1][1] (read p3 this iter, lead 3)
//   p1 reads [0][1], stages t2.kh0->[0][0] (read next p0)
//   p2 reads [1][0], stages t2.kh1->[0][1] (read next p1)
//   p3 reads [1][1], stages t3.kh0->[1][0] (read next p2)
// Uniform vmcnt(6): keeps the newest 2 phases' 6 loads in flight, forces the
// 3-phase-old stage complete -> exactly covers each read (verified by count).
// Last iter: stages t32+ skipped; waits drain 6/6/3/0. Prologue: t0 full +
// t1.kh0 (9 loads) + vmcnt(6) (= t0 landed, t1.kh0 in flight).

__device__ __forceinline__ void stage_halfA(const unsigned short* base, int t, int kh,
                                            unsigned short* half_, int tid) {
#pragma unroll
    for (int j = 0; j < 2; ++j) {
        int idx = j * 512 + tid;              // 256 rows x 4 chunks
        int r = idx >> 2, slot = idx & 3;
        int c4 = slot ^ ((r >> 1) & 3);
        const unsigned short* g = base + (size_t)r * SS + t * 64 + kh * 32 + c4 * 8;
        __builtin_amdgcn_global_load_lds((const __attribute__((address_space(1))) unsigned int*)g,
                                         (__attribute__((address_space(3))) unsigned int*)(half_ + idx * 8),
                                         16, 0, 0);
    }
}

__device__ __forceinline__ void stage_halfB(const unsigned short* base, int t, int kh,
                                            unsigned short* half_, int tid) {
    int r = tid >> 2, slot = tid & 3;         // 128 rows x 4 chunks
    int c4 = slot ^ ((r >> 1) & 3);
    const unsigned short* g = base + (size_t)r * SS + t * 64 + kh * 32 + c4 * 8;
    __builtin_amdgcn_global_load_lds((const __attribute__((address_space(1))) unsigned int*)g,
                                     (__attribute__((address_space(3))) unsigned int*)(half_ + tid * 8),
                                     16, 0, 0);
}

template <int VM>
__device__ __forceinline__ void pv8_phase(const unsigned short* Ah, const unsigned short* Bh,
                                          f4_t acc[8][2],
                                          const unsigned short* Abase, const unsigned short* Bbase,
                                          int st, int skh, unsigned short* dA, unsigned short* dB,
                                          bool sen,
                                          int wm, int wn, int l16, int aslot, int tid) {
    bf8_t af[8];
#pragma unroll
    for (int mi = 0; mi < 8; ++mi)
        af[mi] = *(const bf8_t*)(Ah + (wm * 128 + mi * 16 + l16) * 32 + aslot);
    bf8_t b0 = *(const bf8_t*)(Bh + (wn * 32 + l16) * 32 + aslot);
    bf8_t b1 = *(const bf8_t*)(Bh + (wn * 32 + 16 + l16) * 32 + aslot);
    if (sen) { stage_halfA(Abase, st, skh, dA, tid); stage_halfB(Bbase, st, skh, dB, tid); }
    if (VM == 6)      asm volatile("s_waitcnt vmcnt(6)" ::: "memory");
    else if (VM == 3) asm volatile("s_waitcnt vmcnt(3)" ::: "memory");
    else              asm volatile("s_waitcnt vmcnt(0)" ::: "memory");
    __builtin_amdgcn_s_barrier();
    asm volatile("s_waitcnt lgkmcnt(0)" ::: "memory");
    __builtin_amdgcn_sched_barrier(0);
    __builtin_amdgcn_s_setprio(1);
#pragma unroll
    for (int mi = 0; mi < 8; ++mi) {
        acc[mi][0] = __builtin_amdgcn_mfma_f32_16x16x32_bf16(af[mi], b0, acc[mi][0], 0, 0, 0);
        acc[mi][1] = __builtin_amdgcn_mfma_f32_16x16x32_bf16(af[mi], b1, acc[mi][1], 0, 0, 0);
    }
    __builtin_amdgcn_s_setprio(0);
    __builtin_amdgcn_s_barrier();
    __builtin_amdgcn_sched_barrier(0);
}

__global__ void __launch_bounds__(512, 2) pv8_kernel(const unsigned short* __restrict__ delta,
                                                     const unsigned short* __restrict__ Vt,
                                                     const float* __restrict__ lsum,
                                                     float* __restrict__ out) {
    __shared__ unsigned short Ab[2][2][256 * 32];   // 64 KB
    __shared__ unsigned short Bb[2][2][128 * 32];   // 32 KB
    const int tid = threadIdx.x;
    const int wave = tid >> 6, lane = tid & 63;
    const int wm = wave >> 2, wn = wave & 3;
    const int quad = lane >> 4, l16 = lane & 15;
    const int aslot = (quad ^ ((l16 >> 1) & 3)) * 8;

    const int lin = blockIdx.x;
    const int b = lin & 7;
    const int qT = (lin >> 3) & 7;
    const int eT = lin >> 6;                  // 0..3

    const unsigned short* Abase = delta + ((size_t)b * SS + qT * 256) * SS;
    const unsigned short* Bbase = Vt + ((size_t)b * EE + eT * 128) * SS;

    f4_t acc[8][2];
    const f4_t z = {0.f, 0.f, 0.f, 0.f};
#pragma unroll
    for (int i = 0; i < 8; ++i) { acc[i][0] = z; acc[i][1] = z; }

    // prologue: t0 (4 halves) + t1.kh0 = 9 loads
    stage_halfA(Abase, 0, 0, &Ab[0][0][0], tid); stage_halfB(Bbase, 0, 0, &Bb[0][0][0], tid);
    stage_halfA(Abase, 0, 1, &Ab[0][1][0], tid); stage_halfB(Bbase, 0, 1, &Bb[0][1][0], tid);
    stage_halfA(Abase, 1, 0, &Ab[1][0][0], tid); stage_halfB(Bbase, 1, 0, &Bb[1][0][0], tid);
    asm volatile("s_waitcnt vmcnt(6)" ::: "memory");   // t0 landed
    __builtin_amdgcn_s_barrier();
    __builtin_amdgcn_sched_barrier(0);

#pragma unroll 1
    for (int it = 0; it < 16; ++it) {
        const int t1 = 2 * it + 1, t2 = 2 * it + 2, t3 = 2 * it + 3;
        if (it < 15) {
            pv8_phase<6>(&Ab[0][0][0], &Bb[0][0][0], acc, Abase, Bbase, t1, 1, &Ab[1][1][0], &Bb[1][1][0], true, wm, wn, l16, aslot, tid);
            pv8_phase<6>(&Ab[0][1][0], &Bb[0][1][0], acc, Abase, Bbase, t2, 0, &Ab[0][0][0], &Bb[0][0][0], true, wm, wn, l16, aslot, tid);
            pv8_phase<6>(&Ab[1][0][0], &Bb[1][0][0], acc, Abase, Bbase, t2, 1, &Ab[0][1][0], &Bb[0][1][0], true, wm, wn, l16, aslot, tid);
            pv8_phase<6>(&Ab[1][1][0], &Bb[1][1][0], acc, Abase, Bbase, t3, 0, &Ab[1][0][0], &Bb[1][0][0], true, wm, wn, l16, aslot, tid);
        } else {
            pv8_phase<6>(&Ab[0][0][0], &Bb[0][0][0], acc, Abase, Bbase, t1, 1, &Ab[1][1][0], &Bb[1][1][0], true, wm, wn, l16, aslot, tid);
            pv8_phase<6>(&Ab[0][1][0], &Bb[0][1][0], acc, Abase, Bbase, 0, 0, (unsigned short*)0, (unsigned short*)0, false, wm, wn, l16, aslot, tid);
            pv8_phase<3>(&Ab[1][0][0], &Bb[1][0][0], acc, Abase, Bbase, 0, 0, (unsigned short*)0, (unsigned short*)0, false, wm, wn, l16, aslot, tid);
            pv8_phase<0>(&Ab[1][1][0], &Bb[1][1][0], acc, Abase, Bbase, 0, 0, (unsigned short*)0, (unsigned short*)0, false, wm, wn, l16, aslot, tid);
        }
    }

    // epilogue: normalize and store fp32
#pragma unroll
    for (int mi = 0; mi < 8; ++mi) {
#pragma unroll
        for (int r = 0; r < 4; ++r) {
            const int row = qT * 256 + wm * 128 + mi * 16 + quad * 4 + r;
            const float inv = 1.0f / (lsum[b * SS + row] + 1e-10f);
            const size_t orow = ((size_t)b * SS + row) * EE;
#pragma unroll
            for (int nj = 0; nj < 2; ++nj)
                out[orow + eT * 128 + wn * 32 + nj * 16 + l16] = acc[mi][nj][r] * inv;
        }
    }
}

// ---------------- launcher ----------------

extern "C" void kernel_launch(void* const* d_in, const int* in_sizes, int n_in,
                              void* d_out, int out_size, void* d_ws, size_t ws_size,
                              hipStream_t stream) {
    const int*   key_seq = (const int*)d_in[0];
    const int*   val_seq = (const int*)d_in[1];
    const float* hidden  = (const float*)d_in[2];
    const float* mask    = (const float*)d_in[3];
    // d_in[4] nan_matrix: unused by forward
    const float* key_emb = (const float*)d_in[5];
    const float* val_emb = (const float*)d_in[6];
    const float* weight  = (const float*)d_in[7];
    float* out = (float*)d_out;

    char* ws = (char*)d_ws;
    const size_t SZ_BSE = (size_t)BB * SS * EE * sizeof(unsigned short);  // 16,777,216
    unsigned short* Q    = (unsigned short*)(ws);
    unsigned short* K    = (unsigned short*)(ws + SZ_BSE);
    unsigned short* Vt   = (unsigned short*)(ws + 2 * SZ_BSE);
    unsigned short* H    = (unsigned short*)(ws + 3 * SZ_BSE);
    unsigned short* Wt   = (unsigned short*)(ws + 4 * SZ_BSE);            // 524,288 B
    float*          lsum = (float*)(ws + 4 * SZ_BSE + 524288);           // 65,536 B
    unsigned short* delta= (unsigned short*)(ws + 4 * SZ_BSE + 524288 + 65536); // 67,108,864 B

    hipMemsetAsync(lsum, 0, (size_t)BB * SS * sizeof(float), stream);

    gather_k_kernel<<<4096, 256, 0, stream>>>(key_seq, key_emb, K);
    cast_h_kernel<<<4096, 256, 0, stream>>>(hidden, H);
    gather_vt_kernel<<<4096, 256, 0, stream>>>(val_seq, val_emb, Vt);
    transpose_w_kernel<<<1024, 256, 0, stream>>>(weight, Wt);

    qgen_kernel<<<dim3(4, 128), 256, 0, stream>>>(H, Wt, Q);
    qk8_kernel<<<512, 512, 0, stream>>>(Q, K, mask, delta, lsum);
    pv8_kernel<<<256, 512, 0, stream>>>(delta, Vt, lsum, out);
}